// Round 19
// baseline (681.206 us; speedup 1.0000x reference)
//
#include <hip/hip_runtime.h>

typedef unsigned short u16;
typedef unsigned int u32;
using short8 = __attribute__((ext_vector_type(8))) short;
using f32x4  = __attribute__((ext_vector_type(4))) float;

#define SCALE 0.15811388300841897f  // 40^-0.5

__device__ __forceinline__ u16 f2bf(float f) {
  unsigned int u = __float_as_uint(f);
  u += 0x7fffu + ((u >> 16) & 1u);   // RNE
  return (u16)(u >> 16);
}
__device__ __forceinline__ u32 pack2bf(float a, float b) {
  return (u32)f2bf(a) | ((u32)f2bf(b) << 16);
}

// ---------------- ws layout (u16 units) ----------------
// wqt [320][320]        @ 0        (102400)  Wq^T * SCALE, bf16
// wot [320][320]        @ 102400   (102400)  Wo^T, bf16
// wkt [320][768]        @ 204800   (245760)  Wk^T, bf16
// wvt [320][768]        @ 450560   (245760)  Wv^T, bf16
// kbf [16][8][80][64]   @ 696320   (655360)  K  (m pad->80, d pad->64 zeroed)
// vt  [16][8][48][96]   @ 1351680  (589824)  V^T (d pad->48 zeroed, m pad->96 zeroed)

// ============ kernel 0: LDS-tiled weight transpose + bf16 ============
__global__ void prep_transpose(const float* __restrict__ Wq, const float* __restrict__ Wo,
                               const float* __restrict__ Wk, const float* __restrict__ Wv,
                               u16* __restrict__ wqt, u16* __restrict__ wot,
                               u16* __restrict__ wkt, u16* __restrict__ wvt) {
  __shared__ float ld[64][65];
  const int bid = blockIdx.x;
  const float* src; u16* dst; int K; float scale; int tk, tn;
  if (bid < 25)       { src = Wq; dst = wqt; K = 320; scale = SCALE; tk = bid / 5;         tn = bid % 5; }
  else if (bid < 50)  { src = Wo; dst = wot; K = 320; scale = 1.f;   tk = (bid - 25) / 5;  tn = (bid - 25) % 5; }
  else if (bid < 110) { src = Wk; dst = wkt; K = 768; scale = 1.f;   tk = (bid - 50) / 5;  tn = (bid - 50) % 5; }
  else                { src = Wv; dst = wvt; K = 768; scale = 1.f;   tk = (bid - 110) / 5; tn = (bid - 110) % 5; }
  const int c = threadIdx.x & 63, r0 = threadIdx.x >> 6;
  for (int rr = r0; rr < 64; rr += 4)
    ld[rr][c] = src[(size_t)(tk * 64 + rr) * 320 + tn * 64 + c];
  __syncthreads();
  for (int rr = r0; rr < 64; rr += 4)
    dst[(size_t)(tn * 64 + rr) * K + tk * 64 + c] = f2bf(ld[c][rr] * scale);
}

// ============ kernel 1: K,V projection via MFMA (split K/V) ============
__global__ __launch_bounds__(256, 1)
void kv_mfma(const float* __restrict__ ctx,
             const u16* __restrict__ wkt, const u16* __restrict__ wvt,
             u16* __restrict__ kbf, u16* __restrict__ vt) {
  const int b = blockIdx.x, z = blockIdx.y;
  const int tid = threadIdx.x;
  const int w = tid >> 6, l = tid & 63, l16 = l & 15, lhi = l >> 4;
  __shared__ __align__(16) u16 sctx[80][776];

  for (int i = tid; i < 80 * 192; i += 256) {
    int row = i / 192, c4 = (i - row * 192) * 4;
    ushort4 u;
    if (row < 77) {
      float4 v = *reinterpret_cast<const float4*>(&ctx[(size_t)(b * 77 + row) * 768 + c4]);
      u.x = f2bf(v.x); u.y = f2bf(v.y); u.z = f2bf(v.z); u.w = f2bf(v.w);
    } else u = (ushort4){0, 0, 0, 0};
    *reinterpret_cast<ushort4*>(&sctx[row][c4]) = u;
  }
  if (z == 0) {
    for (int i = tid; i < 8 * 80 * 3; i += 256) {
      int hm = i / 3, q = i - hm * 3;
      int h = hm / 80, m = hm - h * 80;
      *reinterpret_cast<uint4*>(&kbf[(((size_t)b * 8 + h) * 80 + m) * 64 + 40 + q * 8]) = (uint4){0, 0, 0, 0};
    }
  } else {
    for (int i = tid; i < 8 * 48 * 2; i += 256) {
      int hd = i / 2, q = i - hd * 2;
      int h = hd / 48, d = hd - h * 48;
      *reinterpret_cast<uint4*>(&vt[(((size_t)b * 8 + h) * 48 + d) * 96 + 80 + q * 8]) = (uint4){0, 0, 0, 0};
    }
    for (int i = tid; i < 8 * 8 * 10; i += 256) {
      int h = i / 80, rem = i - h * 80;
      int d = 40 + rem / 10, q = rem - (rem / 10) * 10;
      *reinterpret_cast<uint4*>(&vt[(((size_t)b * 8 + h) * 48 + d) * 96 + q * 8]) = (uint4){0, 0, 0, 0};
    }
  }
  __syncthreads();

  f32x4 acc[5][5];
  #pragma unroll
  for (int rt = 0; rt < 5; ++rt)
    #pragma unroll
    for (int nt = 0; nt < 5; ++nt) acc[rt][nt] = (f32x4){0.f, 0.f, 0.f, 0.f};

  const u16* wbase = (z == 0 ? wkt : wvt) + (size_t)(w * 80) * 768;
  #pragma unroll 2
  for (int ks = 0; ks < 24; ++ks) {
    short8 af[5];
    #pragma unroll
    for (int rt = 0; rt < 5; ++rt)
      af[rt] = *reinterpret_cast<const short8*>(&sctx[rt * 16 + l16][ks * 32 + lhi * 8]);
    short8 bf[5];
    #pragma unroll
    for (int nt = 0; nt < 5; ++nt)
      bf[nt] = *reinterpret_cast<const short8*>(&wbase[(size_t)(nt * 16 + l16) * 768 + ks * 32 + lhi * 8]);
    #pragma unroll
    for (int rt = 0; rt < 5; ++rt)
      #pragma unroll
      for (int nt = 0; nt < 5; ++nt)
        acc[rt][nt] = __builtin_amdgcn_mfma_f32_16x16x32_bf16(af[rt], bf[nt], acc[rt][nt], 0, 0, 0);
  }

  if (z == 0) {
    #pragma unroll
    for (int rt = 0; rt < 5; ++rt)
      #pragma unroll
      for (int nt = 0; nt < 5; ++nt) {
        int c = w * 80 + nt * 16 + l16, h = c / 40, d = c - h * 40;
        #pragma unroll
        for (int r = 0; r < 4; ++r) {
          int m = rt * 16 + lhi * 4 + r;
          kbf[(((size_t)b * 8 + h) * 80 + m) * 64 + d] = f2bf(m < 77 ? acc[rt][nt][r] : 0.f);
        }
      }
  } else {
    #pragma unroll
    for (int rt = 0; rt < 5; ++rt)
      #pragma unroll
      for (int nt = 0; nt < 5; ++nt) {
        int c = w * 80 + nt * 16 + l16, h = c / 40, d = c - h * 40;
        #pragma unroll
        for (int r = 0; r < 4; ++r) {
          int m = rt * 16 + lhi * 4 + r;
          vt[(((size_t)b * 8 + h) * 48 + d) * 96 + m] = f2bf(m < 77 ? acc[rt][nt][r] : 0.f);
        }
      }
  }
}

// ============ kernel 2: fused x->Q->attention->out, persistent 2-tile pipeline ============
// R19: grid 512 (exactly 2 blocks/CU resident, no scheduling rounds); each
// block processes tiles g=bid and g=bid+512. x for tile t+1 is loaded into
// REGISTERS (10 float4/thread) right after tile t's LDS staging writes, so
// its HBM latency hides under tile t's entire compute -> continuous HBM
// demand instead of per-block bursts (T14 at tile granularity).
// Phases per tile are R17 verbatim (8 waves, reg-P swapped QK^T, setprio).
__global__ __launch_bounds__(512, 4)
void fused(const float* __restrict__ x, const u16* __restrict__ wqt,
           const u16* __restrict__ kbf, const u16* __restrict__ vtp,
           const u16* __restrict__ wot, const float* __restrict__ bo,
           float* __restrict__ out) {
  const int tid = threadIdx.x;
  const int w   = tid >> 6;       // 0..7
  const int l   = tid & 63;
  const int l16 = l & 15;
  const int lhi = l >> 4;
  const int w2 = w >> 2, w4 = w & 3;

  __shared__ __align__(16) u16 Qx[64][344];      // 44,032 B: x -> Q -> O in place

  const int ctb = (w < 4) ? 3 * w : 2 * w + 4;
  int ctv[3];
  ctv[0] = ctb;
  ctv[1] = (ctb + 1 < 19) ? ctb + 1 : 19;
  ctv[2] = (ctb + 2 < 19) ? ctb + 2 : 19;

  // zero pad cols 320..343 once (no phase ever writes them)
  for (int i = tid; i < 64 * 3; i += 512) {
    int row = i / 3, q = i - row * 3;
    *reinterpret_cast<uint4*>(&Qx[row][320 + q * 8]) = (uint4){0u, 0u, 0u, 0u};
  }

  // prologue: load tile 0's x into registers
  float4 xbuf[10];
  {
    const int g = blockIdx.x;
    const int b = (g & 7) + 8 * ((g >> 3) & 1);
    const int q0 = (g >> 4) * 64;
    const float4* xin = reinterpret_cast<const float4*>(x + (size_t)(b * 4096 + q0) * 320);
    #pragma unroll
    for (int k = 0; k < 10; ++k) xbuf[k] = xin[tid + k * 512];
  }

  for (int tau = 0; tau < 2; ++tau) {
    const int g = blockIdx.x + tau * 512;
    const int b = (g & 7) + 8 * ((g >> 3) & 1);
    const int q0 = (g >> 4) * 64;

    // --- stage x regs -> bf16 LDS ---
    #pragma unroll
    for (int k = 0; k < 10; ++k) {
      int i = tid + k * 512;
      int row = i / 80, c4 = (i - row * 80) * 4;
      ushort4 u;
      u.x = f2bf(xbuf[k].x); u.y = f2bf(xbuf[k].y);
      u.z = f2bf(xbuf[k].z); u.w = f2bf(xbuf[k].w);
      *reinterpret_cast<ushort4*>(&Qx[row][c4]) = u;
    }
    // issue NEXT tile's x loads (latency hides under this tile's full compute)
    if (tau == 0) {
      const int g2 = blockIdx.x + 512;
      const int b2 = (g2 & 7) + 8 * ((g2 >> 3) & 1);
      const int q02 = (g2 >> 4) * 64;
      const float4* xin2 = reinterpret_cast<const float4*>(x + (size_t)(b2 * 4096 + q02) * 320);
      #pragma unroll
      for (int k = 0; k < 10; ++k) xbuf[k] = xin2[tid + k * 512];
    }
    __syncthreads();

    // --- Phase 1: Q-GEMM, all 64 rows x this wave's 3 col-tiles ---
    {
      f32x4 qacc[4][3];
      #pragma unroll
      for (int rt = 0; rt < 4; ++rt)
        #pragma unroll
        for (int nt = 0; nt < 3; ++nt) qacc[rt][nt] = (f32x4){0.f, 0.f, 0.f, 0.f};
      #pragma unroll
      for (int ks = 0; ks < 10; ++ks) {
        short8 af[4];
        #pragma unroll
        for (int rt = 0; rt < 4; ++rt)
          af[rt] = *reinterpret_cast<const short8*>(&Qx[rt * 16 + l16][ks * 32 + lhi * 8]);
        short8 bf[3];
        #pragma unroll
        for (int nt = 0; nt < 3; ++nt)
          bf[nt] = *reinterpret_cast<const short8*>(
              &wqt[(size_t)(ctv[nt] * 16 + l16) * 320 + ks * 32 + lhi * 8]);
        #pragma unroll
        for (int nt = 0; nt < 3; ++nt)
          #pragma unroll
          for (int rt = 0; rt < 4; ++rt)
            qacc[rt][nt] = __builtin_amdgcn_mfma_f32_16x16x32_bf16(af[rt], bf[nt], qacc[rt][nt], 0, 0, 0);
      }
      __syncthreads();   // all x reads done before overwrite
      #pragma unroll
      for (int nt = 0; nt < 3; ++nt) {
        int col = ctv[nt] * 16 + l16;
        #pragma unroll
        for (int rt = 0; rt < 4; ++rt)
          #pragma unroll
          for (int r = 0; r < 4; ++r)
            Qx[rt * 16 + lhi * 4 + r][col] = f2bf(qacc[rt][nt][r]);
      }
    }
    __syncthreads();

    // --- Phase 2: attention, swapped QK^T + register-P + K half-prefetch ---
    {
      const int wq = w & 3, hg = w >> 2;
      const int srcLo = ((lhi & 1) << 5) + l16;
      const int srcHi = srcLo + 16;
      const bool hiSel = (lhi >= 2);

      short8 kbuf[2][5];
      {
        const u16* kh0 = kbf + (size_t)(b * 8 + hg * 4) * 80 * 64;
        #pragma unroll
        for (int mt = 0; mt < 5; ++mt)
          kbuf[0][mt] = *reinterpret_cast<const short8*>(&kh0[(mt * 16 + l16) * 64 + lhi * 8]);
      }

      #pragma unroll
      for (int hi4 = 0; hi4 < 4; ++hi4) {
        const int h = hg * 4 + hi4;
        const int cur = hi4 & 1;
        const u16* kh = kbf + (size_t)(b * 8 + h) * 80 * 64;
        const u16* vh = vtp + (size_t)(b * 8 + h) * 48 * 96;
        if (hi4 < 3) {
          const u16* khn = kh + 80 * 64;
          #pragma unroll
          for (int mt = 0; mt < 5; ++mt)
            kbuf[cur ^ 1][mt] = *reinterpret_cast<const short8*>(&khn[(mt * 16 + l16) * 64 + lhi * 8]);
        }
        short8 qk0 = *reinterpret_cast<const short8*>(&Qx[wq * 16 + l16][h * 40 + lhi * 8]);
        short8 qk1 = *reinterpret_cast<const short8*>(&Qx[wq * 16 + l16][h * 40 + 32 + lhi * 8]);
        f32x4 sacc[5];
        #pragma unroll
        for (int mt = 0; mt < 5; ++mt) sacc[mt] = (f32x4){0.f, 0.f, 0.f, 0.f};
        __builtin_amdgcn_s_setprio(1);
        #pragma unroll
        for (int mt = 0; mt < 5; ++mt) {
          sacc[mt] = __builtin_amdgcn_mfma_f32_16x16x32_bf16(kbuf[cur][mt], qk0, sacc[mt], 0, 0, 0);
          short8 ka1 = *reinterpret_cast<const short8*>(&kh[(mt * 16 + l16) * 64 + 32 + lhi * 8]);
          sacc[mt] = __builtin_amdgcn_mfma_f32_16x16x32_bf16(ka1, qk1, sacc[mt], 0, 0, 0);
        }
        __builtin_amdgcn_s_setprio(0);
        float psum = 0.f;
        #pragma unroll
        for (int mt = 0; mt < 5; ++mt)
          #pragma unroll
          for (int r = 0; r < 4; ++r) {
            float e = __expf(sacc[mt][r]);
            if (mt == 4 && lhi * 4 + r >= 13) e = 0.f;   // m = 64+lhi*4+r >= 77
            sacc[mt][r] = e;
            psum += e;
          }
        psum += __shfl_xor(psum, 16);
        psum += __shfl_xor(psum, 32);
        float rs = 1.f / psum;
        u32 pk[5][2];
        #pragma unroll
        for (int mt = 0; mt < 5; ++mt) {
          pk[mt][0] = pack2bf(sacc[mt][0] * rs, sacc[mt][1] * rs);
          pk[mt][1] = pack2bf(sacc[mt][2] * rs, sacc[mt][3] * rs);
        }
        uint4 fr[3];
        #pragma unroll
        for (int ks = 0; ks < 2; ++ks) {
          const int mtA = 2 * ks, mtB = 2 * ks + 1;
          u32 a0 = (u32)__shfl((int)pk[mtA][0], srcLo);
          u32 a1 = (u32)__shfl((int)pk[mtA][1], srcLo);
          u32 a2 = (u32)__shfl((int)pk[mtA][0], srcHi);
          u32 a3 = (u32)__shfl((int)pk[mtA][1], srcHi);
          u32 b0 = (u32)__shfl((int)pk[mtB][0], srcLo);
          u32 b1 = (u32)__shfl((int)pk[mtB][1], srcLo);
          u32 b2 = (u32)__shfl((int)pk[mtB][0], srcHi);
          u32 b3 = (u32)__shfl((int)pk[mtB][1], srcHi);
          fr[ks] = (uint4){hiSel ? b0 : a0, hiSel ? b1 : a1, hiSel ? b2 : a2, hiSel ? b3 : a3};
        }
        {   // ks=2: mt=4; hi lanes map to m>=80 -> zero
          u32 a0 = (u32)__shfl((int)pk[4][0], srcLo);
          u32 a1 = (u32)__shfl((int)pk[4][1], srcLo);
          u32 a2 = (u32)__shfl((int)pk[4][0], srcHi);
          u32 a3 = (u32)__shfl((int)pk[4][1], srcHi);
          fr[2] = (uint4){hiSel ? 0u : a0, hiSel ? 0u : a1, hiSel ? 0u : a2, hiSel ? 0u : a3};
        }
        f32x4 oacc[3];
        #pragma unroll
        for (int nt = 0; nt < 3; ++nt) oacc[nt] = (f32x4){0.f, 0.f, 0.f, 0.f};
        __builtin_amdgcn_s_setprio(1);
        #pragma unroll
        for (int ks = 0; ks < 3; ++ks) {
          union { uint4 u; short8 s; } cv;
          cv.u = fr[ks];
          #pragma unroll
          for (int nt = 0; nt < 3; ++nt) {
            short8 bb = *reinterpret_cast<const short8*>(&vh[(nt * 16 + l16) * 96 + ks * 32 + lhi * 8]);
            oacc[nt] = __builtin_amdgcn_mfma_f32_16x16x32_bf16(cv.s, bb, oacc[nt], 0, 0, 0);
          }
        }
        __builtin_amdgcn_s_setprio(0);
        #pragma unroll
        for (int nt = 0; nt < 3; ++nt) {
          int d = nt * 16 + l16;
          if (d < 40) {
            #pragma unroll
            for (int r = 0; r < 4; ++r)
              Qx[wq * 16 + lhi * 4 + r][h * 40 + d] = f2bf(oacc[nt][r]);
          }
        }
      }
    }
    __syncthreads();

    // --- Phase 3: out = O @ Wo^T + bo (wave: rows 32*w2, cols 80*w4) ---
    {
      f32x4 cacc[2][5];
      #pragma unroll
      for (int rt = 0; rt < 2; ++rt)
        #pragma unroll
        for (int nt = 0; nt < 5; ++nt) cacc[rt][nt] = (f32x4){0.f, 0.f, 0.f, 0.f};
      #pragma unroll
      for (int ks = 0; ks < 10; ++ks) {
        short8 af[2];
        #pragma unroll
        for (int rt = 0; rt < 2; ++rt)
          af[rt] = *reinterpret_cast<const short8*>(&Qx[w2 * 32 + rt * 16 + l16][ks * 32 + lhi * 8]);
        #pragma unroll
        for (int nt = 0; nt < 5; ++nt) {
          short8 bf = *reinterpret_cast<const short8*>(
              &wot[(size_t)(w4 * 80 + nt * 16 + l16) * 320 + ks * 32 + lhi * 8]);
          #pragma unroll
          for (int rt = 0; rt < 2; ++rt)
            cacc[rt][nt] = __builtin_amdgcn_mfma_f32_16x16x32_bf16(af[rt], bf, cacc[rt][nt], 0, 0, 0);
        }
      }
      #pragma unroll
      for (int nt = 0; nt < 5; ++nt) {
        int col = w4 * 80 + nt * 16 + l16;
        float bias = bo[col];
        #pragma unroll
        for (int rt = 0; rt < 2; ++rt) {
          #pragma unroll
          for (int r = 0; r < 4; ++r) {
            int row = w2 * 32 + rt * 16 + lhi * 4 + r;
            out[(size_t)(b * 4096 + q0 + row) * 320 + col] = cacc[rt][nt][r] + bias;
          }
        }
      }
    }
    __syncthreads();   // P3 Qx reads done before next tile's staging overwrites
  }
}

extern "C" void kernel_launch(void* const* d_in, const int* in_sizes, int n_in,
                              void* d_out, int out_size, void* d_ws, size_t ws_size,
                              hipStream_t stream) {
  (void)in_sizes; (void)n_in; (void)out_size; (void)ws_size;
  const float* x       = (const float*)d_in[0];
  const float* context = (const float*)d_in[1];
  const float* Wq      = (const float*)d_in[2];
  const float* Wk      = (const float*)d_in[3];
  const float* Wv      = (const float*)d_in[4];
  const float* Wo      = (const float*)d_in[5];
  const float* bo      = (const float*)d_in[6];
  float* out = (float*)d_out;
  u16* ws = (u16*)d_ws;
  u16* wqt = ws;                 // 102400
  u16* wot = ws + 102400;        // 102400
  u16* wkt = ws + 204800;        // 245760
  u16* wvt = ws + 450560;        // 245760
  u16* kbf = ws + 696320;        // 655360
  u16* vtp = ws + 1351680;       // 589824

  prep_transpose<<<170, 256, 0, stream>>>(Wq, Wo, Wk, Wv, wqt, wot, wkt, wvt);
  kv_mfma<<<dim3(16, 2), 256, 0, stream>>>(context, wkt, wvt, kbf, vtp);
  fused<<<512, 512, 0, stream>>>(x, wqt, kbf, vtp, wot, bo, out);
}

// Round 20
// 186.463 us; speedup vs baseline: 3.6533x; 3.6533x over previous
//
#include <hip/hip_runtime.h>

typedef unsigned short u16;
typedef unsigned int u32;
using short8 = __attribute__((ext_vector_type(8))) short;
using f32x4  = __attribute__((ext_vector_type(4))) float;

#define SCALE 0.15811388300841897f     // 40^-0.5
#define SCALE_L2E 0.22810749f          // 40^-0.5 * log2(e): scores come out in log2-domain

__device__ __forceinline__ u16 f2bf(float f) {
  unsigned int u = __float_as_uint(f);
  u += 0x7fffu + ((u >> 16) & 1u);   // RNE
  return (u16)(u >> 16);
}
__device__ __forceinline__ u32 pack2bf(float a, float b) {
  return (u32)f2bf(a) | ((u32)f2bf(b) << 16);
}

// ---------------- ws layout (u16 units) ----------------
// wqt [320][320]        @ 0        (102400)  Wq^T * SCALE*log2e, bf16
// wot [320][320]        @ 102400   (102400)  Wo^T, bf16
// wkt [320][768]        @ 204800   (245760)  Wk^T, bf16
// wvt [320][768]        @ 450560   (245760)  Wv^T, bf16
// kbf [16][8][80][64]   @ 696320   (655360)  K  (m pad->80, d pad->64 zeroed)
// vt  [16][8][48][96]   @ 1351680  (589824)  V^T (d pad->48 zeroed, m pad->96 zeroed)

// ============ kernel 0: LDS-tiled weight transpose + bf16 ============
__global__ void prep_transpose(const float* __restrict__ Wq, const float* __restrict__ Wo,
                               const float* __restrict__ Wk, const float* __restrict__ Wv,
                               u16* __restrict__ wqt, u16* __restrict__ wot,
                               u16* __restrict__ wkt, u16* __restrict__ wvt) {
  __shared__ float ld[64][65];
  const int bid = blockIdx.x;
  const float* src; u16* dst; int K; float scale; int tk, tn;
  if (bid < 25)       { src = Wq; dst = wqt; K = 320; scale = SCALE_L2E; tk = bid / 5;         tn = bid % 5; }
  else if (bid < 50)  { src = Wo; dst = wot; K = 320; scale = 1.f;       tk = (bid - 25) / 5;  tn = (bid - 25) % 5; }
  else if (bid < 110) { src = Wk; dst = wkt; K = 768; scale = 1.f;       tk = (bid - 50) / 5;  tn = (bid - 50) % 5; }
  else                { src = Wv; dst = wvt; K = 768; scale = 1.f;       tk = (bid - 110) / 5; tn = (bid - 110) % 5; }
  const int c = threadIdx.x & 63, r0 = threadIdx.x >> 6;
  for (int rr = r0; rr < 64; rr += 4)
    ld[rr][c] = src[(size_t)(tk * 64 + rr) * 320 + tn * 64 + c];
  __syncthreads();
  for (int rr = r0; rr < 64; rr += 4)
    dst[(size_t)(tn * 64 + rr) * K + tk * 64 + c] = f2bf(ld[c][rr] * scale);
}

// ============ kernel 1: K,V projection via MFMA (split K/V) ============
__global__ __launch_bounds__(256, 1)
void kv_mfma(const float* __restrict__ ctx,
             const u16* __restrict__ wkt, const u16* __restrict__ wvt,
             u16* __restrict__ kbf, u16* __restrict__ vt) {
  const int b = blockIdx.x, z = blockIdx.y;
  const int tid = threadIdx.x;
  const int w = tid >> 6, l = tid & 63, l16 = l & 15, lhi = l >> 4;
  __shared__ __align__(16) u16 sctx[80][776];

  for (int i = tid; i < 80 * 192; i += 256) {
    int row = i / 192, c4 = (i - row * 192) * 4;
    ushort4 u;
    if (row < 77) {
      float4 v = *reinterpret_cast<const float4*>(&ctx[(size_t)(b * 77 + row) * 768 + c4]);
      u.x = f2bf(v.x); u.y = f2bf(v.y); u.z = f2bf(v.z); u.w = f2bf(v.w);
    } else u = (ushort4){0, 0, 0, 0};
    *reinterpret_cast<ushort4*>(&sctx[row][c4]) = u;
  }
  if (z == 0) {
    for (int i = tid; i < 8 * 80 * 3; i += 256) {
      int hm = i / 3, q = i - hm * 3;
      int h = hm / 80, m = hm - h * 80;
      *reinterpret_cast<uint4*>(&kbf[(((size_t)b * 8 + h) * 80 + m) * 64 + 40 + q * 8]) = (uint4){0, 0, 0, 0};
    }
  } else {
    for (int i = tid; i < 8 * 48 * 2; i += 256) {
      int hd = i / 2, q = i - hd * 2;
      int h = hd / 48, d = hd - h * 48;
      *reinterpret_cast<uint4*>(&vt[(((size_t)b * 8 + h) * 48 + d) * 96 + 80 + q * 8]) = (uint4){0, 0, 0, 0};
    }
    for (int i = tid; i < 8 * 8 * 10; i += 256) {
      int h = i / 80, rem = i - h * 80;
      int d = 40 + rem / 10, q = rem - (rem / 10) * 10;
      *reinterpret_cast<uint4*>(&vt[(((size_t)b * 8 + h) * 48 + d) * 96 + q * 8]) = (uint4){0, 0, 0, 0};
    }
  }
  __syncthreads();

  f32x4 acc[5][5];
  #pragma unroll
  for (int rt = 0; rt < 5; ++rt)
    #pragma unroll
    for (int nt = 0; nt < 5; ++nt) acc[rt][nt] = (f32x4){0.f, 0.f, 0.f, 0.f};

  const u16* wbase = (z == 0 ? wkt : wvt) + (size_t)(w * 80) * 768;
  #pragma unroll 2
  for (int ks = 0; ks < 24; ++ks) {
    short8 af[5];
    #pragma unroll
    for (int rt = 0; rt < 5; ++rt)
      af[rt] = *reinterpret_cast<const short8*>(&sctx[rt * 16 + l16][ks * 32 + lhi * 8]);
    short8 bf[5];
    #pragma unroll
    for (int nt = 0; nt < 5; ++nt)
      bf[nt] = *reinterpret_cast<const short8*>(&wbase[(size_t)(nt * 16 + l16) * 768 + ks * 32 + lhi * 8]);
    #pragma unroll
    for (int rt = 0; rt < 5; ++rt)
      #pragma unroll
      for (int nt = 0; nt < 5; ++nt)
        acc[rt][nt] = __builtin_amdgcn_mfma_f32_16x16x32_bf16(af[rt], bf[nt], acc[rt][nt], 0, 0, 0);
  }

  if (z == 0) {
    #pragma unroll
    for (int rt = 0; rt < 5; ++rt)
      #pragma unroll
      for (int nt = 0; nt < 5; ++nt) {
        int c = w * 80 + nt * 16 + l16, h = c / 40, d = c - h * 40;
        #pragma unroll
        for (int r = 0; r < 4; ++r) {
          int m = rt * 16 + lhi * 4 + r;
          kbf[(((size_t)b * 8 + h) * 80 + m) * 64 + d] = f2bf(m < 77 ? acc[rt][nt][r] : 0.f);
        }
      }
  } else {
    #pragma unroll
    for (int rt = 0; rt < 5; ++rt)
      #pragma unroll
      for (int nt = 0; nt < 5; ++nt) {
        int c = w * 80 + nt * 16 + l16, h = c / 40, d = c - h * 40;
        #pragma unroll
        for (int r = 0; r < 4; ++r) {
          int m = rt * 16 + lhi * 4 + r;
          vt[(((size_t)b * 8 + h) * 48 + d) * 96 + m] = f2bf(m < 77 ? acc[rt][nt][r] : 0.f);
        }
      }
  }
}

// ============ kernel 2: fully fused x->Q->attention->out (R17 structure) ============
// 512 thr (8 waves), LDS 44 KB, launch_bounds(512,4) — the proven no-spill point.
// Batch-grouping XCD swizzle; reg-P swapped QK^T; K half-prefetch; setprio.
// R20 micro-opts: scores in log2-domain (exp2f, v_exp native) + fast rcp.
__global__ __launch_bounds__(512, 4)
void fused(const float* __restrict__ x, const u16* __restrict__ wqt,
           const u16* __restrict__ kbf, const u16* __restrict__ vtp,
           const u16* __restrict__ wot, const float* __restrict__ bo,
           float* __restrict__ out) {
  const int bid = blockIdx.x;
  const int b  = (bid & 7) + 8 * ((bid >> 3) & 1);
  const int q0 = (bid >> 4) * 64;
  const int tid = threadIdx.x;
  const int w   = tid >> 6;       // 0..7
  const int l   = tid & 63;
  const int l16 = l & 15;
  const int lhi = l >> 4;
  const int w2 = w >> 2, w4 = w & 3;

  __shared__ __align__(16) u16 Qx[64][344];      // 44,032 B: x -> Q -> O in place

  const int ctb = (w < 4) ? 3 * w : 2 * w + 4;
  int ctv[3];
  ctv[0] = ctb;
  ctv[1] = (ctb + 1 < 19) ? ctb + 1 : 19;
  ctv[2] = (ctb + 2 < 19) ? ctb + 2 : 19;

  // --- stage x -> bf16 LDS; zero pad cols 320..343 ---
  const float4* xin = reinterpret_cast<const float4*>(x + (size_t)(b * 4096 + q0) * 320);
  for (int i = tid; i < 64 * 80; i += 512) {
    float4 v = xin[i];
    int row = i / 80, c4 = (i - row * 80) * 4;
    ushort4 u;
    u.x = f2bf(v.x); u.y = f2bf(v.y); u.z = f2bf(v.z); u.w = f2bf(v.w);
    *reinterpret_cast<ushort4*>(&Qx[row][c4]) = u;
  }
  for (int i = tid; i < 64 * 3; i += 512) {
    int row = i / 3, q = i - row * 3;
    *reinterpret_cast<uint4*>(&Qx[row][320 + q * 8]) = (uint4){0u, 0u, 0u, 0u};
  }
  __syncthreads();

  // --- Phase 1: Q-GEMM, all 64 rows x this wave's 3 col-tiles ---
  {
    f32x4 qacc[4][3];
    #pragma unroll
    for (int rt = 0; rt < 4; ++rt)
      #pragma unroll
      for (int nt = 0; nt < 3; ++nt) qacc[rt][nt] = (f32x4){0.f, 0.f, 0.f, 0.f};
    #pragma unroll
    for (int ks = 0; ks < 10; ++ks) {
      short8 af[4];
      #pragma unroll
      for (int rt = 0; rt < 4; ++rt)
        af[rt] = *reinterpret_cast<const short8*>(&Qx[rt * 16 + l16][ks * 32 + lhi * 8]);
      short8 bf[3];
      #pragma unroll
      for (int nt = 0; nt < 3; ++nt)
        bf[nt] = *reinterpret_cast<const short8*>(
            &wqt[(size_t)(ctv[nt] * 16 + l16) * 320 + ks * 32 + lhi * 8]);
      #pragma unroll
      for (int nt = 0; nt < 3; ++nt)
        #pragma unroll
        for (int rt = 0; rt < 4; ++rt)
          qacc[rt][nt] = __builtin_amdgcn_mfma_f32_16x16x32_bf16(af[rt], bf[nt], qacc[rt][nt], 0, 0, 0);
    }
    __syncthreads();   // all x reads done before overwrite
    #pragma unroll
    for (int nt = 0; nt < 3; ++nt) {
      int col = ctv[nt] * 16 + l16;
      #pragma unroll
      for (int rt = 0; rt < 4; ++rt)
        #pragma unroll
        for (int r = 0; r < 4; ++r)
          Qx[rt * 16 + lhi * 4 + r][col] = f2bf(qacc[rt][nt][r]);
    }
  }
  __syncthreads();

  // --- Phase 2: attention, swapped QK^T + register-P + K half-prefetch ---
  {
    const int wq = w & 3, hg = w >> 2;
    const int srcLo = ((lhi & 1) << 5) + l16;
    const int srcHi = srcLo + 16;
    const bool hiSel = (lhi >= 2);

    // prefetch ks=0 K-frags for first head
    short8 kbuf[2][5];
    {
      const u16* kh0 = kbf + (size_t)(b * 8 + hg * 4) * 80 * 64;
      #pragma unroll
      for (int mt = 0; mt < 5; ++mt)
        kbuf[0][mt] = *reinterpret_cast<const short8*>(&kh0[(mt * 16 + l16) * 64 + lhi * 8]);
    }

    #pragma unroll
    for (int hi4 = 0; hi4 < 4; ++hi4) {
      const int h = hg * 4 + hi4;
      const int cur = hi4 & 1;
      const u16* kh = kbf + (size_t)(b * 8 + h) * 80 * 64;
      const u16* vh = vtp + (size_t)(b * 8 + h) * 48 * 96;
      // issue next head's ks=0 K loads early (latency hides under this head)
      if (hi4 < 3) {
        const u16* khn = kh + 80 * 64;
        #pragma unroll
        for (int mt = 0; mt < 5; ++mt)
          kbuf[cur ^ 1][mt] = *reinterpret_cast<const short8*>(&khn[(mt * 16 + l16) * 64 + lhi * 8]);
      }
      // Q B-frags from LDS (per-head; overrun cols finite x K-pad zeros -> 0)
      short8 qk0 = *reinterpret_cast<const short8*>(&Qx[wq * 16 + l16][h * 40 + lhi * 8]);
      short8 qk1 = *reinterpret_cast<const short8*>(&Qx[wq * 16 + l16][h * 40 + 32 + lhi * 8]);
      // S^T = K @ Q^T: lane (l16,lhi) holds S[m = mt*16 + lhi*4 + r][q = l16]
      f32x4 sacc[5];
      #pragma unroll
      for (int mt = 0; mt < 5; ++mt) sacc[mt] = (f32x4){0.f, 0.f, 0.f, 0.f};
      __builtin_amdgcn_s_setprio(1);
      #pragma unroll
      for (int mt = 0; mt < 5; ++mt) {
        sacc[mt] = __builtin_amdgcn_mfma_f32_16x16x32_bf16(kbuf[cur][mt], qk0, sacc[mt], 0, 0, 0);
        short8 ka1 = *reinterpret_cast<const short8*>(&kh[(mt * 16 + l16) * 64 + 32 + lhi * 8]);
        sacc[mt] = __builtin_amdgcn_mfma_f32_16x16x32_bf16(ka1, qk1, sacc[mt], 0, 0, 0);
      }
      __builtin_amdgcn_s_setprio(0);
      // lane-local softmax; scores already in log2 domain (2^t = e^s exactly)
      float psum = 0.f;
      #pragma unroll
      for (int mt = 0; mt < 5; ++mt)
        #pragma unroll
        for (int r = 0; r < 4; ++r) {
          float e = exp2f(sacc[mt][r]);
          if (mt == 4 && lhi * 4 + r >= 13) e = 0.f;   // m = 64+lhi*4+r >= 77
          sacc[mt][r] = e;
          psum += e;
        }
      psum += __shfl_xor(psum, 16);
      psum += __shfl_xor(psum, 32);
      float rs = __builtin_amdgcn_rcpf(psum);
      u32 pk[5][2];
      #pragma unroll
      for (int mt = 0; mt < 5; ++mt) {
        pk[mt][0] = pack2bf(sacc[mt][0] * rs, sacc[mt][1] * rs);
        pk[mt][1] = pack2bf(sacc[mt][2] * rs, sacc[mt][3] * rs);
      }
      // build PV A-frags in-register: frag[ks] elem e = P[q=l16][m=ks*32+lhi*8+e]
      uint4 fr[3];
      #pragma unroll
      for (int ks = 0; ks < 2; ++ks) {
        const int mtA = 2 * ks, mtB = 2 * ks + 1;
        u32 a0 = (u32)__shfl((int)pk[mtA][0], srcLo);
        u32 a1 = (u32)__shfl((int)pk[mtA][1], srcLo);
        u32 a2 = (u32)__shfl((int)pk[mtA][0], srcHi);
        u32 a3 = (u32)__shfl((int)pk[mtA][1], srcHi);
        u32 b0 = (u32)__shfl((int)pk[mtB][0], srcLo);
        u32 b1 = (u32)__shfl((int)pk[mtB][1], srcLo);
        u32 b2 = (u32)__shfl((int)pk[mtB][0], srcHi);
        u32 b3 = (u32)__shfl((int)pk[mtB][1], srcHi);
        fr[ks] = (uint4){hiSel ? b0 : a0, hiSel ? b1 : a1, hiSel ? b2 : a2, hiSel ? b3 : a3};
      }
      {   // ks=2: mt=4; hi lanes map to m>=80 -> zero
        u32 a0 = (u32)__shfl((int)pk[4][0], srcLo);
        u32 a1 = (u32)__shfl((int)pk[4][1], srcLo);
        u32 a2 = (u32)__shfl((int)pk[4][0], srcHi);
        u32 a3 = (u32)__shfl((int)pk[4][1], srcHi);
        fr[2] = (uint4){hiSel ? 0u : a0, hiSel ? 0u : a1, hiSel ? 0u : a2, hiSel ? 0u : a3};
      }
      // O = P @ V
      f32x4 oacc[3];
      #pragma unroll
      for (int nt = 0; nt < 3; ++nt) oacc[nt] = (f32x4){0.f, 0.f, 0.f, 0.f};
      __builtin_amdgcn_s_setprio(1);
      #pragma unroll
      for (int ks = 0; ks < 3; ++ks) {
        union { uint4 u; short8 s; } cv;
        cv.u = fr[ks];
        #pragma unroll
        for (int nt = 0; nt < 3; ++nt) {
          short8 bb = *reinterpret_cast<const short8*>(&vh[(nt * 16 + l16) * 96 + ks * 32 + lhi * 8]);
          oacc[nt] = __builtin_amdgcn_mfma_f32_16x16x32_bf16(cv.s, bb, oacc[nt], 0, 0, 0);
        }
      }
      __builtin_amdgcn_s_setprio(0);
      // O -> Qx in place (own rows, head-h cols)
      #pragma unroll
      for (int nt = 0; nt < 3; ++nt) {
        int d = nt * 16 + l16;
        if (d < 40) {
          #pragma unroll
          for (int r = 0; r < 4; ++r)
            Qx[wq * 16 + lhi * 4 + r][h * 40 + d] = f2bf(oacc[nt][r]);
        }
      }
    }
  }
  __syncthreads();

  // --- Phase 3: out = O @ Wo^T + bo (wave: rows 32*w2, cols 80*w4) ---
  {
    f32x4 cacc[2][5];
    #pragma unroll
    for (int rt = 0; rt < 2; ++rt)
      #pragma unroll
      for (int nt = 0; nt < 5; ++nt) cacc[rt][nt] = (f32x4){0.f, 0.f, 0.f, 0.f};
    #pragma unroll
    for (int ks = 0; ks < 10; ++ks) {
      short8 af[2];
      #pragma unroll
      for (int rt = 0; rt < 2; ++rt)
        af[rt] = *reinterpret_cast<const short8*>(&Qx[w2 * 32 + rt * 16 + l16][ks * 32 + lhi * 8]);
      #pragma unroll
      for (int nt = 0; nt < 5; ++nt) {
        short8 bf = *reinterpret_cast<const short8*>(
            &wot[(size_t)(w4 * 80 + nt * 16 + l16) * 320 + ks * 32 + lhi * 8]);
        #pragma unroll
        for (int rt = 0; rt < 2; ++rt)
          cacc[rt][nt] = __builtin_amdgcn_mfma_f32_16x16x32_bf16(af[rt], bf, cacc[rt][nt], 0, 0, 0);
      }
    }
    #pragma unroll
    for (int nt = 0; nt < 5; ++nt) {
      int col = w4 * 80 + nt * 16 + l16;
      float bias = bo[col];
      #pragma unroll
      for (int rt = 0; rt < 2; ++rt) {
        #pragma unroll
        for (int r = 0; r < 4; ++r) {
          int row = w2 * 32 + rt * 16 + lhi * 4 + r;
          out[(size_t)(b * 4096 + q0 + row) * 320 + col] = cacc[rt][nt][r] + bias;
        }
      }
    }
  }
}

extern "C" void kernel_launch(void* const* d_in, const int* in_sizes, int n_in,
                              void* d_out, int out_size, void* d_ws, size_t ws_size,
                              hipStream_t stream) {
  (void)in_sizes; (void)n_in; (void)out_size; (void)ws_size;
  const float* x       = (const float*)d_in[0];
  const float* context = (const float*)d_in[1];
  const float* Wq      = (const float*)d_in[2];
  const float* Wk      = (const float*)d_in[3];
  const float* Wv      = (const float*)d_in[4];
  const float* Wo      = (const float*)d_in[5];
  const float* bo      = (const float*)d_in[6];
  float* out = (float*)d_out;
  u16* ws = (u16*)d_ws;
  u16* wqt = ws;                 // 102400
  u16* wot = ws + 102400;        // 102400
  u16* wkt = ws + 204800;        // 245760
  u16* wvt = ws + 450560;        // 245760
  u16* kbf = ws + 696320;        // 655360
  u16* vtp = ws + 1351680;       // 589824

  prep_transpose<<<170, 256, 0, stream>>>(Wq, Wo, Wk, Wv, wqt, wot, wkt, wvt);
  kv_mfma<<<dim3(16, 2), 256, 0, stream>>>(context, wkt, wvt, kbf, vtp);
  fused<<<1024, 512, 0, stream>>>(x, wqt, kbf, vtp, wot, bo, out);
}